// Round 10
// baseline (736.804 us; speedup 1.0000x reference)
//
#include <hip/hip_runtime.h>
#include <hip/hip_bf16.h>

#define NN 20000
#define EE 320000
#define RR 8
#define NR (NN * RR)
#define NB 40     // scan blocks per graph: ceil(160000/4096)
#define SCAP 640  // LDS edge-window capacity for 32 rows (mean 512, sd ~23)

typedef float f32x4 __attribute__((ext_vector_type(4)));
typedef short s16x8 __attribute__((ext_vector_type(8)));

__device__ __forceinline__ unsigned short f2bf(float f) {
  unsigned u = __builtin_bit_cast(unsigned, f);
  unsigned r = u + 0x7FFFu + ((u >> 16) & 1u);
  return (unsigned short)(r >> 16);
}
__device__ __forceinline__ float bf2f(unsigned short u) {
  return __builtin_bit_cast(float, (unsigned)u << 16);
}
__device__ __forceinline__ void gload_lds16(const void* g, void* l) {
  __builtin_amdgcn_global_load_lds(
      (const __attribute__((address_space(1))) unsigned*)g,
      (__attribute__((address_space(3))) unsigned*)l, 16, 0, 0);
}

// ---- per-(graph,dst,relation) segment count, both graphs ----
__global__ void k_count(const int* __restrict__ ei, const int* __restrict__ et,
                        int* __restrict__ cnt) {
  int e = blockIdx.x * blockDim.x + threadIdx.x;  // 0..2*EE
  int g = e >= EE;
  int el = e - g * EE;
  int d = ei[(size_t)g * 2 * EE + EE + el];
  int t = et[(size_t)g * EE + el];
  atomicAdd(&cnt[(size_t)g * NR + d * RR + t], 1);
}

// ---- hierarchical exclusive scan ----
__global__ __launch_bounds__(1024) void k_scan1(const int* __restrict__ cnt,
                                                int* __restrict__ off,
                                                int* __restrict__ btot) {
  int g = blockIdx.y, b = blockIdx.x;
  const int* c = cnt + (size_t)g * NR;
  int* o = off + (size_t)g * NR;
  __shared__ int wsum[16];
  int lane = threadIdx.x & 63, w = threadIdx.x >> 6;
  int i = b * 4096 + (int)threadIdx.x * 4;
  int4 v = {0, 0, 0, 0};
  if (i + 3 < NR) v = *(const int4*)&c[i];
  else {
    if (i < NR) v.x = c[i];
    if (i + 1 < NR) v.y = c[i + 1];
    if (i + 2 < NR) v.z = c[i + 2];
  }
  int s0 = v.x, s1 = s0 + v.y, s2 = s1 + v.z, s3 = s2 + v.w;
  int s = s3;
  for (int d = 1; d < 64; d <<= 1) {
    int t = __shfl_up(s, d);
    if (lane >= d) s += t;
  }
  if (lane == 63) wsum[w] = s;
  __syncthreads();
  if (threadIdx.x < 16) {
    int ws = wsum[threadIdx.x];
    for (int d = 1; d < 16; d <<= 1) {
      int t = __shfl_up(ws, d);
      if ((int)threadIdx.x >= d) ws += t;
    }
    wsum[threadIdx.x] = ws;
  }
  __syncthreads();
  int excl = (w > 0 ? wsum[w - 1] : 0) + (s - s3);
  if (i < NR) o[i] = excl;
  if (i + 1 < NR) o[i + 1] = excl + s0;
  if (i + 2 < NR) o[i + 2] = excl + s1;
  if (i + 3 < NR) o[i + 3] = excl + s2;
  if (threadIdx.x == 0) btot[g * NB + b] = wsum[15];
}

__global__ void k_scan2(const int* __restrict__ btot, int* __restrict__ bof) {
  int g = threadIdx.x >> 6, lane = threadIdx.x & 63;
  int v = (lane < NB) ? btot[g * NB + lane] : 0;
  int s = v;
  for (int d = 1; d < 64; d <<= 1) {
    int t = __shfl_up(s, d);
    if (lane >= d) s += t;
  }
  if (lane < NB) bof[g * NB + lane] = s - v;
}

__global__ __launch_bounds__(1024) void k_scan3(int* __restrict__ off,
                                                const int* __restrict__ bof) {
  int g = blockIdx.y;
  int add = bof[g * NB + blockIdx.x];
  int i = blockIdx.x * 4096 + (int)threadIdx.x * 4;
  int* o = off + (size_t)g * NR;
  if (i + 3 < NR) {
    int4 v = *(const int4*)&o[i];
    v.x += add; v.y += add; v.z += add; v.w += add;
    *(int4*)&o[i] = v;
  } else {
    for (int j = i; j < NR; ++j) o[j] += add;
  }
}

// ---- scatter src ids; DESTROYS off: post-scatter off[s] = end of segment s ----
__global__ void k_scatter(const int* __restrict__ ei, const int* __restrict__ et,
                          int* __restrict__ off, int* __restrict__ ssrc) {
  int e = blockIdx.x * blockDim.x + threadIdx.x;
  int g = e >= EE;
  int el = e - g * EE;
  int s = ei[(size_t)g * 2 * EE + el];
  int d = ei[(size_t)g * 2 * EE + EE + el];
  int t = et[(size_t)g * EE + el];
  int pos = atomicAdd(&off[(size_t)g * NR + d * RR + t], 1);
  ssrc[(size_t)g * EE + pos] = s;
}

// ---- fp32 x -> bf16, both graphs, into per-graph NN*256-strided slots ----
__global__ void k_cvt(const float* __restrict__ x, unsigned short* __restrict__ hX) {
  int i = (blockIdx.x * blockDim.x + threadIdx.x) * 4;
  if (i >= 2 * NN * 128) return;
  int g = i >= NN * 128;
  int il = i - g * NN * 128;
  float4 v = *(const float4*)&x[i];
  ushort4 o;
  o.x = f2bf(v.x); o.y = f2bf(v.y); o.z = f2bf(v.z); o.w = f2bf(v.w);
  *(ushort4*)&hX[(size_t)g * NN * 256 + il] = o;
}

// ---- bf16 transposed weight panel BT[co][k], k = r*Cin+ci (r=8 -> root) ----
__global__ void k_bt(const float* __restrict__ W, const float* __restrict__ root,
                     unsigned short* __restrict__ bt, int Cin, int Cout, int Ktot) {
  int idx = blockIdx.x * blockDim.x + threadIdx.x;
  if (idx >= Cout * Ktot) return;
  int co = idx / Ktot, k = idx - co * Ktot;
  int r = k / Cin, ci = k - r * Cin;
  float v = (r < RR) ? W[((size_t)r * Cin + ci) * Cout + co]
                     : root[(size_t)ci * Cout + co];
  bt[idx] = f2bf(v);
}

// B frags straight from global bt into registers (L2-resident panel)
#define LOADB(bb, k0)                                                          \
  _Pragma("unroll") for (int kk = 0; kk < 2; ++kk)                             \
      _Pragma("unroll") for (int f = 0; f < 4; ++f) bb[kk][f] =                \
          *(const s16x8*)(btw + (size_t)f * 16 * KTOT + (k0) + kk * 32);

// MFMA over As sub-tile c (64 k-cols) with B regs bb
#define MFMA_STEP_C(c, bb)                                                     \
  do {                                                                         \
    _Pragma("unroll") for (int kk = 0; kk < 2; ++kk) {                         \
      s16x8 a[MF];                                                             \
      _Pragma("unroll") for (int f = 0; f < MF; ++f) {                         \
        int row = wm + f * 16 + (lane & 15);                                   \
        int colb = kk * 64 + (lane >> 4) * 16;                                 \
        a[f] = *(const s16x8*)((const char*)As + (c)*4096 + row * 128 +        \
                               (colb ^ ((row & 7) << 4)));                     \
      }                                                                        \
      _Pragma("unroll") for (int fm = 0; fm < MF; ++fm)                        \
          _Pragma("unroll") for (int fn = 0; fn < 4; ++fn)                     \
              acc[fm][fn] = __builtin_amdgcn_mfma_f32_16x16x32_bf16(           \
                  a[fm], bb[kk][fn], acc[fm][fn], 0, 0, 0);                    \
    }                                                                          \
  } while (0)

// ---- fused gather+GEMM, 32-row x COUT tile, relation-granular barriers ----
template <int CIN, int COUT, bool OUTF32>
__global__ __launch_bounds__(256) void k_fused(
    const int* __restrict__ ssrc, const int* __restrict__ off,
    const unsigned short* __restrict__ h, const unsigned short* __restrict__ bt,
    const float* __restrict__ bias, void* __restrict__ outp) {
  constexpr int KTOT = (RR + 1) * CIN;
  constexpr int CH = CIN / 64;     // K-steps (sub-tiles) per relation (2 or 4)
  constexpr int CPT = CIN / 8;     // cols per thread in walk (16 or 32)
  constexpr int NCH = CPT / 8;     // 16B chunks per thread (2 or 4)
  constexpr int NWN = COUT / 64;   // n-waves (4 or 2)
  constexpr int MW = 4 / NWN;      // m-waves (1 or 2)
  constexpr int WR = 32 / MW;      // rows per wave (32 or 16)
  constexpr int MF = WR / 16;      // m-frags per wave (2 or 1)
  __shared__ unsigned short As[CH * 32 * 64];  // sub-tile major, full CIN
  __shared__ int offs[32][9];      // per-row segment boundaries (start + 8 ends)
  __shared__ int sseg[SCAP];       // this block's sorted-edge window
  const int tid = threadIdx.x, lane = tid & 63, wave = tid >> 6;
  const int wn = (wave % NWN) * 64;
  const int wm = (wave / NWN) * WR;
  const int m0 = blockIdx.x * 32;  // NN == 625*32, no clamps needed
  const int g = blockIdx.z;
  ssrc += (size_t)g * EE;
  off += (size_t)g * NR;
  h += (size_t)g * NN * 256;

  for (int idx = tid; idx < 32 * 9; idx += 256) {
    int row = idx / 9, j = idx - row * 9;
    int seg0 = (m0 + row) * RR;
    offs[row][j] = (j == 0) ? (seg0 == 0 ? 0 : off[seg0 - 1]) : off[seg0 + j - 1];
  }
  const int segA = m0 * RR;
  const int ebase = (segA == 0) ? 0 : off[segA - 1];
  const int eend = off[(m0 + 32) * RR - 1];
  const int cntE = eend - ebase;
  const bool inl = cntE <= SCAP;
  if (inl)
    for (int i = tid; i < cntE; i += 256) sseg[i] = ssrc[ebase + i];
  __syncthreads();

  f32x4 acc[MF][4] = {};
  const int arow = tid >> 3;              // this thread's A row (0..31)
  const int q = tid & 7;                  // 8 threads/row, CPT cols each
  const int swzA = (arow & 7) << 4;
  const unsigned short* hq = h + q * CPT;
  const unsigned short* btw = bt + (size_t)(wn + (lane & 15)) * KTOT +
                              (lane >> 4) * 8;

  for (int r = 0; r <= RR; ++r) {
    s16x8 mb[NCH];
    if (r < RR) {
      // ---- walk this relation's segment ONCE, CPT-col fp32 accumulation ----
      float fa[NCH][8];
#pragma unroll
      for (int c = 0; c < NCH; ++c)
#pragma unroll
        for (int j = 0; j < 8; ++j) fa[c][j] = 0.f;
      int o0 = offs[arow][r], o1 = offs[arow][r + 1];
      int e = o0;
      for (; e + 1 < o1; e += 2) {
        int sa = inl ? sseg[e - ebase] : ssrc[e];
        int sb = inl ? sseg[e + 1 - ebase] : ssrc[e + 1];
        const unsigned short* pa = hq + (size_t)sa * CIN;
        const unsigned short* pb = hq + (size_t)sb * CIN;
#pragma unroll
        for (int c = 0; c < NCH; ++c) {
          s16x8 va = *(const s16x8*)(pa + c * 8);
          s16x8 vb = *(const s16x8*)(pb + c * 8);
#pragma unroll
          for (int j = 0; j < 8; ++j)
            fa[c][j] += bf2f((unsigned short)va[j]) + bf2f((unsigned short)vb[j]);
        }
      }
      if (e < o1) {
        int sa = inl ? sseg[e - ebase] : ssrc[e];
        const unsigned short* pa = hq + (size_t)sa * CIN;
#pragma unroll
        for (int c = 0; c < NCH; ++c) {
          s16x8 va = *(const s16x8*)(pa + c * 8);
#pragma unroll
          for (int j = 0; j < 8; ++j) fa[c][j] += bf2f((unsigned short)va[j]);
        }
      }
      float inv = 1.0f / fmaxf((float)(o1 - o0), 1.0f);
#pragma unroll
      for (int c = 0; c < NCH; ++c)
#pragma unroll
        for (int j = 0; j < 8; ++j) mb[c][j] = (short)f2bf(fa[c][j] * inv);
    }
    __syncthreads();  // prior relation's MFMA done reading As
    if (r < RR) {
      // write this thread's CPT cols into the sub-tile-major swizzled As
#pragma unroll
      for (int ch = 0; ch < NCH; ++ch) {
        int colb = (q * CPT + ch * 8) * 2;  // byte col in full CIN row
        int ct = colb >> 7;                 // sub-tile index
        int wb = colb & 127;                // byte within 128-B window
        *(s16x8*)((char*)As + ct * 4096 + arow * 128 + (wb ^ swzA)) = mb[ch];
      }
    } else {
      // root term: stage h rows directly via global_load_lds (pre-swizzled src)
#pragma unroll
      for (int i = 0; i < CH; ++i) {
        int o = i * 4096 + wave * 1024;  // wave-uniform LDS base
        int ob = o + lane * 16;
        int row = (ob >> 7) & 31;
        int wb = ob & 127;
        gload_lds16((const char*)h + ((size_t)(m0 + row) * CIN + i * 64) * 2 +
                        (wb ^ ((row & 7) << 4)),
                    (char*)As + o);
      }
    }
    __syncthreads();  // As ready (drains gload_lds / ds_writes)
    const int rk0 = r * CIN;
    {
      s16x8 bc[2][4], bn[2][4];
      LOADB(bc, rk0);
#pragma unroll
      for (int c = 0; c < CH; ++c) {
        if (c + 1 < CH) { LOADB(bn, rk0 + (c + 1) * 64); }
        MFMA_STEP_C(c, bc);
        if (c + 1 < CH) {
#pragma unroll
          for (int kk = 0; kk < 2; ++kk)
#pragma unroll
            for (int f = 0; f < 4; ++f) bc[kk][f] = bn[kk][f];
        }
      }
    }
  }
  // ---- epilogue: bias + LeakyReLU ----
#pragma unroll
  for (int fm = 0; fm < MF; ++fm) {
    int rbase = m0 + wm + fm * 16 + (lane >> 4) * 4;
#pragma unroll
    for (int fn = 0; fn < 4; ++fn) {
      int col = wn + fn * 16 + (lane & 15);
      float bv = bias[col];
#pragma unroll
      for (int v = 0; v < 4; ++v) {
        int row = rbase + v;
        float xv = acc[fm][fn][v] + bv;
        xv = xv > 0.f ? xv : 0.2f * xv;
        if constexpr (OUTF32)
          ((float*)outp)[(size_t)g * NN * COUT + (size_t)row * COUT + col] = xv;
        else
          ((unsigned short*)outp)[(size_t)g * NN * 256 + (size_t)row * COUT +
                                  col] = f2bf(xv);
      }
    }
  }
}

extern "C" void kernel_launch(void* const* d_in, const int* in_sizes, int n_in,
                              void* d_out, int out_size, void* d_ws, size_t ws_size,
                              hipStream_t stream) {
  const float* x  = (const float*)d_in[0];
  const int* ei   = (const int*)d_in[1];
  const int* etp  = (const int*)d_in[2];
  const float* W0 = (const float*)d_in[3];
  const float* r0 = (const float*)d_in[4];
  const float* b0 = (const float*)d_in[5];
  const float* W1 = (const float*)d_in[6];
  const float* r1 = (const float*)d_in[7];
  const float* b1 = (const float*)d_in[8];
  const float* W2 = (const float*)d_in[9];
  const float* r2 = (const float*)d_in[10];
  const float* b2 = (const float*)d_in[11];

  char* p = (char*)d_ws;
  unsigned short* hX  = (unsigned short*)p; p += (size_t)2 * NN * 256 * 2;
  unsigned short* h_a = (unsigned short*)p; p += (size_t)2 * NN * 256 * 2;
  int* cnt  = (int*)p; p += (size_t)2 * NR * 4;
  int* off  = (int*)p; p += (size_t)2 * NR * 4;
  int* btot = (int*)p; p += (size_t)2 * NB * 4;
  int* bof  = (int*)p; p += (size_t)2 * NB * 4;
  int* ssrc = (int*)p; p += (size_t)2 * EE * 4;
  unsigned short* bt0 = (unsigned short*)p; p += (size_t)256 * 1152 * 2;
  unsigned short* bt1 = (unsigned short*)p; p += (size_t)256 * 2304 * 2;
  unsigned short* bt2 = (unsigned short*)p; p += (size_t)128 * 2304 * 2;

  // weight panels (graph-independent)
  k_bt<<<(256 * 1152 + 255) / 256, 256, 0, stream>>>(W0, r0, bt0, 128, 256, 1152);
  k_bt<<<(256 * 2304 + 255) / 256, 256, 0, stream>>>(W1, r1, bt1, 256, 256, 2304);
  k_bt<<<(128 * 2304 + 255) / 256, 256, 0, stream>>>(W2, r2, bt2, 256, 128, 2304);

  // edge sort (both graphs batched)
  (void)hipMemsetAsync(cnt, 0, (size_t)2 * NR * 4, stream);
  k_count<<<2 * EE / 256, 256, 0, stream>>>(ei, etp, cnt);
  k_scan1<<<dim3(NB, 2), 1024, 0, stream>>>(cnt, off, btot);
  k_scan2<<<1, 128, 0, stream>>>(btot, bof);
  k_scan3<<<dim3(NB, 2), 1024, 0, stream>>>(off, bof);
  k_cvt<<<2 * NN * 128 / 4 / 256, 256, 0, stream>>>(x, hX);
  k_scatter<<<2 * EE / 256, 256, 0, stream>>>(ei, etp, off, ssrc);

  // layer 0: 128 -> 256 (fused gather+GEMM)
  k_fused<128, 256, false><<<dim3(625, 1, 2), 256, 0, stream>>>(
      ssrc, off, hX, bt0, b0, h_a);
  // layer 1: 256 -> 256
  k_fused<256, 256, false><<<dim3(625, 1, 2), 256, 0, stream>>>(
      ssrc, off, h_a, bt1, b1, hX);
  // layer 2: 256 -> 128
  k_fused<256, 128, true><<<dim3(625, 1, 2), 256, 0, stream>>>(
      ssrc, off, hX, bt2, b2, d_out);
}

// Round 11
// 420.288 us; speedup vs baseline: 1.7531x; 1.7531x over previous
//
#include <hip/hip_runtime.h>
#include <hip/hip_bf16.h>

#define NN 20000
#define EE 320000
#define RR 8
#define NR (NN * RR)
#define NB 40     // scan blocks per graph: ceil(160000/4096)
#define SCAP 640  // LDS edge-window capacity for 32 rows (mean 512, sd ~23)

typedef float f32x4 __attribute__((ext_vector_type(4)));
typedef short s16x8 __attribute__((ext_vector_type(8)));

__device__ __forceinline__ unsigned short f2bf(float f) {
  unsigned u = __builtin_bit_cast(unsigned, f);
  unsigned r = u + 0x7FFFu + ((u >> 16) & 1u);
  return (unsigned short)(r >> 16);
}
__device__ __forceinline__ float bf2f(unsigned short u) {
  return __builtin_bit_cast(float, (unsigned)u << 16);
}
__device__ __forceinline__ void gload_lds16(const void* g, void* l) {
  __builtin_amdgcn_global_load_lds(
      (const __attribute__((address_space(1))) unsigned*)g,
      (__attribute__((address_space(3))) unsigned*)l, 16, 0, 0);
}

// ---- per-(graph,dst,relation) segment count, both graphs ----
__global__ void k_count(const int* __restrict__ ei, const int* __restrict__ et,
                        int* __restrict__ cnt) {
  int e = blockIdx.x * blockDim.x + threadIdx.x;  // 0..2*EE
  int g = e >= EE;
  int el = e - g * EE;
  int d = ei[(size_t)g * 2 * EE + EE + el];
  int t = et[(size_t)g * EE + el];
  atomicAdd(&cnt[(size_t)g * NR + d * RR + t], 1);
}

// ---- hierarchical exclusive scan ----
__global__ __launch_bounds__(1024) void k_scan1(const int* __restrict__ cnt,
                                                int* __restrict__ off,
                                                int* __restrict__ btot) {
  int g = blockIdx.y, b = blockIdx.x;
  const int* c = cnt + (size_t)g * NR;
  int* o = off + (size_t)g * NR;
  __shared__ int wsum[16];
  int lane = threadIdx.x & 63, w = threadIdx.x >> 6;
  int i = b * 4096 + (int)threadIdx.x * 4;
  int4 v = {0, 0, 0, 0};
  if (i + 3 < NR) v = *(const int4*)&c[i];
  else {
    if (i < NR) v.x = c[i];
    if (i + 1 < NR) v.y = c[i + 1];
    if (i + 2 < NR) v.z = c[i + 2];
  }
  int s0 = v.x, s1 = s0 + v.y, s2 = s1 + v.z, s3 = s2 + v.w;
  int s = s3;
  for (int d = 1; d < 64; d <<= 1) {
    int t = __shfl_up(s, d);
    if (lane >= d) s += t;
  }
  if (lane == 63) wsum[w] = s;
  __syncthreads();
  if (threadIdx.x < 16) {
    int ws = wsum[threadIdx.x];
    for (int d = 1; d < 16; d <<= 1) {
      int t = __shfl_up(ws, d);
      if ((int)threadIdx.x >= d) ws += t;
    }
    wsum[threadIdx.x] = ws;
  }
  __syncthreads();
  int excl = (w > 0 ? wsum[w - 1] : 0) + (s - s3);
  if (i < NR) o[i] = excl;
  if (i + 1 < NR) o[i + 1] = excl + s0;
  if (i + 2 < NR) o[i + 2] = excl + s1;
  if (i + 3 < NR) o[i + 3] = excl + s2;
  if (threadIdx.x == 0) btot[g * NB + b] = wsum[15];
}

__global__ void k_scan2(const int* __restrict__ btot, int* __restrict__ bof) {
  int g = threadIdx.x >> 6, lane = threadIdx.x & 63;
  int v = (lane < NB) ? btot[g * NB + lane] : 0;
  int s = v;
  for (int d = 1; d < 64; d <<= 1) {
    int t = __shfl_up(s, d);
    if (lane >= d) s += t;
  }
  if (lane < NB) bof[g * NB + lane] = s - v;
}

__global__ __launch_bounds__(1024) void k_scan3(int* __restrict__ off,
                                                const int* __restrict__ bof) {
  int g = blockIdx.y;
  int add = bof[g * NB + blockIdx.x];
  int i = blockIdx.x * 4096 + (int)threadIdx.x * 4;
  int* o = off + (size_t)g * NR;
  if (i + 3 < NR) {
    int4 v = *(const int4*)&o[i];
    v.x += add; v.y += add; v.z += add; v.w += add;
    *(int4*)&o[i] = v;
  } else {
    for (int j = i; j < NR; ++j) o[j] += add;
  }
}

// ---- scatter src ids; DESTROYS off: post-scatter off[s] = end of segment s ----
__global__ void k_scatter(const int* __restrict__ ei, const int* __restrict__ et,
                          int* __restrict__ off, int* __restrict__ ssrc) {
  int e = blockIdx.x * blockDim.x + threadIdx.x;
  int g = e >= EE;
  int el = e - g * EE;
  int s = ei[(size_t)g * 2 * EE + el];
  int d = ei[(size_t)g * 2 * EE + EE + el];
  int t = et[(size_t)g * EE + el];
  int pos = atomicAdd(&off[(size_t)g * NR + d * RR + t], 1);
  ssrc[(size_t)g * EE + pos] = s;
}

// ---- fp32 x -> bf16, both graphs, into per-graph NN*256-strided slots ----
__global__ void k_cvt(const float* __restrict__ x, unsigned short* __restrict__ hX) {
  int i = (blockIdx.x * blockDim.x + threadIdx.x) * 4;
  if (i >= 2 * NN * 128) return;
  int g = i >= NN * 128;
  int il = i - g * NN * 128;
  float4 v = *(const float4*)&x[i];
  ushort4 o;
  o.x = f2bf(v.x); o.y = f2bf(v.y); o.z = f2bf(v.z); o.w = f2bf(v.w);
  *(ushort4*)&hX[(size_t)g * NN * 256 + il] = o;
}

// ---- fragment-ordered bf16 weight panel:
// btf[((s*(Cout/16)+fr)*2+kk)*512 + lane*8 + j] = BT[co][k]
//   co = fr*16 + (lane&15);  k = s*64 + kk*32 + (lane>>4)*8 + j  (r=8 -> root)
__global__ void k_btf(const float* __restrict__ W, const float* __restrict__ root,
                      unsigned short* __restrict__ btf, int Cin, int Cout,
                      int Ktot) {
  int idx = blockIdx.x * blockDim.x + threadIdx.x;
  if (idx >= Cout * Ktot) return;
  int j = idx & 7;
  int lane = (idx >> 3) & 63;
  int kk = (idx >> 9) & 1;
  int t = idx >> 10;  // s*(Cout/16) + fr
  int fr = t % (Cout / 16);
  int s = t / (Cout / 16);
  int co = fr * 16 + (lane & 15);
  int k = s * 64 + kk * 32 + (lane >> 4) * 8 + j;
  int r = k / Cin, ci = k - r * Cin;
  float v = (r < RR) ? W[((size_t)r * Cin + ci) * Cout + co]
                     : root[(size_t)ci * Cout + co];
  btf[idx] = f2bf(v);
}

// coalesced B-frag load for step s: per (kk,f) 64 lanes read contiguous 1KB
#define LOADB(bb, s)                                                           \
  _Pragma("unroll") for (int kk = 0; kk < 2; ++kk)                             \
      _Pragma("unroll") for (int f = 0; f < 4; ++f) bb[kk][f] =                \
          *(const s16x8*)(btl +                                                \
                          (size_t)(((s) * (COUT / 16) + wn16 + f) * 2 + kk) *  \
                              512);

#define COPYB()                                                                \
  _Pragma("unroll") for (int kk = 0; kk < 2; ++kk)                             \
      _Pragma("unroll") for (int f = 0; f < 4; ++f) bc[kk][f] = bn[kk][f];

// MFMA over As sub-tile c with B regs bb (As stride ASTR breaks bank alignment)
#define MFMA_STEP_C(c, bb)                                                     \
  do {                                                                         \
    _Pragma("unroll") for (int kk = 0; kk < 2; ++kk) {                         \
      s16x8 a[MF];                                                             \
      _Pragma("unroll") for (int f = 0; f < MF; ++f) {                         \
        int row = wm + f * 16 + (lane & 15);                                   \
        int colb = kk * 64 + (lane >> 4) * 16;                                 \
        a[f] = *(const s16x8*)(As + (c)*ASTR + row * 128 +                     \
                               (colb ^ ((row & 7) << 4)));                     \
      }                                                                        \
      _Pragma("unroll") for (int fm = 0; fm < MF; ++fm)                        \
          _Pragma("unroll") for (int fn = 0; fn < 4; ++fn)                     \
              acc[fm][fn] = __builtin_amdgcn_mfma_f32_16x16x32_bf16(           \
                  a[fm], bb[kk][fn], acc[fm][fn], 0, 0, 0);                    \
    }                                                                          \
  } while (0)

// ---- fused gather+GEMM, 32-row x COUT tile, relation-granular barriers,
//      B in registers via fragment-ordered coalesced loads ----
template <int CIN, int COUT, bool OUTF32>
__global__ __launch_bounds__(256) void k_fused(
    const int* __restrict__ ssrc, const int* __restrict__ off,
    const unsigned short* __restrict__ h, const unsigned short* __restrict__ btf,
    const float* __restrict__ bias, void* __restrict__ outp) {
  constexpr int KTOT = (RR + 1) * CIN;
  constexpr int NS = KTOT / 64;    // flat K-steps (18 or 36)
  constexpr int CH = CIN / 64;     // sub-tiles per relation (2 or 4)
  constexpr int CPT = CIN / 8;     // cols per thread in walk (16 or 32)
  constexpr int NCH = CPT / 8;     // 16B chunks per thread (2 or 4)
  constexpr int NWN = COUT / 64;   // n-waves (4 or 2)
  constexpr int MW = 4 / NWN;      // m-waves (1 or 2)
  constexpr int WR = 32 / MW;      // rows per wave (32 or 16)
  constexpr int MF = WR / 16;      // m-frags per wave (2 or 1)
  constexpr int ASTR = 4112;       // padded sub-tile stride (4096+16, not %128)
  __shared__ char As[CH * ASTR];
  __shared__ int offs[32][9];      // per-row segment boundaries (start + 8 ends)
  __shared__ int sseg[SCAP];       // this block's sorted-edge window
  const int tid = threadIdx.x, lane = tid & 63, wave = tid >> 6;
  const int wn = (wave % NWN) * 64;
  const int wn16 = wn >> 4;
  const int wm = (wave / NWN) * WR;
  const int m0 = blockIdx.x * 32;  // NN == 625*32, no clamps needed
  const int g = blockIdx.z;
  ssrc += (size_t)g * EE;
  off += (size_t)g * NR;
  h += (size_t)g * NN * 256;

  for (int idx = tid; idx < 32 * 9; idx += 256) {
    int row = idx / 9, j = idx - row * 9;
    int seg0 = (m0 + row) * RR;
    offs[row][j] = (j == 0) ? (seg0 == 0 ? 0 : off[seg0 - 1]) : off[seg0 + j - 1];
  }
  const int segA = m0 * RR;
  const int ebase = (segA == 0) ? 0 : off[segA - 1];
  const int eend = off[(m0 + 32) * RR - 1];
  const int cntE = eend - ebase;
  const bool inl = cntE <= SCAP;
  if (inl)
    for (int i = tid; i < cntE; i += 256) sseg[i] = ssrc[ebase + i];
  __syncthreads();

  f32x4 acc[MF][4] = {};
  const int arow = tid >> 3;              // this thread's A row (0..31)
  const int q = tid & 7;                  // 8 threads/row, CPT cols each
  const int swzA = (arow & 7) << 4;
  const unsigned short* hq = h + q * CPT;
  const unsigned short* btl = btf + lane * 8;

  s16x8 bc[2][4], bn[2][4];
  LOADB(bc, 0);

  for (int r = 0; r <= RR; ++r) {
    s16x8 mb[NCH];
    if (r < RR) {
      // ---- walk this relation's segment ONCE, CPT-col fp32 accumulation ----
      float fa[NCH][8];
#pragma unroll
      for (int c = 0; c < NCH; ++c)
#pragma unroll
        for (int j = 0; j < 8; ++j) fa[c][j] = 0.f;
      int o0 = offs[arow][r], o1 = offs[arow][r + 1];
      int e = o0;
      for (; e + 1 < o1; e += 2) {
        int sa = inl ? sseg[e - ebase] : ssrc[e];
        int sb = inl ? sseg[e + 1 - ebase] : ssrc[e + 1];
        const unsigned short* pa = hq + (size_t)sa * CIN;
        const unsigned short* pb = hq + (size_t)sb * CIN;
#pragma unroll
        for (int c = 0; c < NCH; ++c) {
          s16x8 va = *(const s16x8*)(pa + c * 8);
          s16x8 vb = *(const s16x8*)(pb + c * 8);
#pragma unroll
          for (int j = 0; j < 8; ++j)
            fa[c][j] += bf2f((unsigned short)va[j]) + bf2f((unsigned short)vb[j]);
        }
      }
      if (e < o1) {
        int sa = inl ? sseg[e - ebase] : ssrc[e];
        const unsigned short* pa = hq + (size_t)sa * CIN;
#pragma unroll
        for (int c = 0; c < NCH; ++c) {
          s16x8 va = *(const s16x8*)(pa + c * 8);
#pragma unroll
          for (int j = 0; j < 8; ++j) fa[c][j] += bf2f((unsigned short)va[j]);
        }
      }
      float inv = 1.0f / fmaxf((float)(o1 - o0), 1.0f);
#pragma unroll
      for (int c = 0; c < NCH; ++c)
#pragma unroll
        for (int j = 0; j < 8; ++j) mb[c][j] = (short)f2bf(fa[c][j] * inv);
    }
    __syncthreads();  // prior relation's MFMA done reading As
    if (r < RR) {
      // write this thread's CPT cols into padded sub-tile-major swizzled As
#pragma unroll
      for (int ch = 0; ch < NCH; ++ch) {
        int colb = (q * CPT + ch * 8) * 2;  // byte col in full CIN row
        int ct = colb >> 7;                 // sub-tile index
        int wb = colb & 127;                // byte within 128-B window
        *(s16x8*)(As + ct * ASTR + arow * 128 + (wb ^ swzA)) = mb[ch];
      }
    } else {
      // root term: stage h rows via global_load_lds (pre-swizzled source)
#pragma unroll
      for (int i = 0; i < CH; ++i) {
        int o = i * ASTR + wave * 1024;  // wave-uniform LDS base
        int ob = wave * 1024 + lane * 16;
        int row = (ob >> 7) & 31;
        int wb = ob & 127;
        gload_lds16((const char*)h + ((size_t)(m0 + row) * CIN + i * 64) * 2 +
                        (wb ^ ((row & 7) << 4)),
                    As + o);
      }
    }
    __syncthreads();  // As visible (drains gload_lds / ds_writes)
#pragma unroll
    for (int c = 0; c < CH; ++c) {
      int s = r * CH + c;
      if (s + 1 < NS) { LOADB(bn, s + 1); }
      MFMA_STEP_C(c, bc);
      if (s + 1 < NS) { COPYB(); }
    }
  }
  // ---- epilogue: bias + LeakyReLU ----
#pragma unroll
  for (int fm = 0; fm < MF; ++fm) {
    int rbase = m0 + wm + fm * 16 + (lane >> 4) * 4;
#pragma unroll
    for (int fn = 0; fn < 4; ++fn) {
      int col = wn + fn * 16 + (lane & 15);
      float bv = bias[col];
#pragma unroll
      for (int v = 0; v < 4; ++v) {
        int row = rbase + v;
        float xv = acc[fm][fn][v] + bv;
        xv = xv > 0.f ? xv : 0.2f * xv;
        if constexpr (OUTF32)
          ((float*)outp)[(size_t)g * NN * COUT + (size_t)row * COUT + col] = xv;
        else
          ((unsigned short*)outp)[(size_t)g * NN * 256 + (size_t)row * COUT +
                                  col] = f2bf(xv);
      }
    }
  }
}

extern "C" void kernel_launch(void* const* d_in, const int* in_sizes, int n_in,
                              void* d_out, int out_size, void* d_ws, size_t ws_size,
                              hipStream_t stream) {
  const float* x  = (const float*)d_in[0];
  const int* ei   = (const int*)d_in[1];
  const int* etp  = (const int*)d_in[2];
  const float* W0 = (const float*)d_in[3];
  const float* r0 = (const float*)d_in[4];
  const float* b0 = (const float*)d_in[5];
  const float* W1 = (const float*)d_in[6];
  const float* r1 = (const float*)d_in[7];
  const float* b1 = (const float*)d_in[8];
  const float* W2 = (const float*)d_in[9];
  const float* r2 = (const float*)d_in[10];
  const float* b2 = (const float*)d_in[11];

  char* p = (char*)d_ws;
  unsigned short* hX  = (unsigned short*)p; p += (size_t)2 * NN * 256 * 2;
  unsigned short* h_a = (unsigned short*)p; p += (size_t)2 * NN * 256 * 2;
  int* cnt  = (int*)p; p += (size_t)2 * NR * 4;
  int* off  = (int*)p; p += (size_t)2 * NR * 4;
  int* btot = (int*)p; p += (size_t)2 * NB * 4;
  int* bof  = (int*)p; p += (size_t)2 * NB * 4;
  int* ssrc = (int*)p; p += (size_t)2 * EE * 4;
  unsigned short* bt0 = (unsigned short*)p; p += (size_t)256 * 1152 * 2;
  unsigned short* bt1 = (unsigned short*)p; p += (size_t)256 * 2304 * 2;
  unsigned short* bt2 = (unsigned short*)p; p += (size_t)128 * 2304 * 2;

  // fragment-ordered weight panels (graph-independent)
  k_btf<<<(256 * 1152 + 255) / 256, 256, 0, stream>>>(W0, r0, bt0, 128, 256, 1152);
  k_btf<<<(256 * 2304 + 255) / 256, 256, 0, stream>>>(W1, r1, bt1, 256, 256, 2304);
  k_btf<<<(128 * 2304 + 255) / 256, 256, 0, stream>>>(W2, r2, bt2, 256, 128, 2304);

  // edge sort (both graphs batched)
  (void)hipMemsetAsync(cnt, 0, (size_t)2 * NR * 4, stream);
  k_count<<<2 * EE / 256, 256, 0, stream>>>(ei, etp, cnt);
  k_scan1<<<dim3(NB, 2), 1024, 0, stream>>>(cnt, off, btot);
  k_scan2<<<1, 128, 0, stream>>>(btot, bof);
  k_scan3<<<dim3(NB, 2), 1024, 0, stream>>>(off, bof);
  k_cvt<<<2 * NN * 128 / 4 / 256, 256, 0, stream>>>(x, hX);
  k_scatter<<<2 * EE / 256, 256, 0, stream>>>(ei, etp, off, ssrc);

  // layer 0: 128 -> 256 (fused gather+GEMM)
  k_fused<128, 256, false><<<dim3(625, 1, 2), 256, 0, stream>>>(
      ssrc, off, hX, bt0, b0, h_a);
  // layer 1: 256 -> 256
  k_fused<256, 256, false><<<dim3(625, 1, 2), 256, 0, stream>>>(
      ssrc, off, h_a, bt1, b1, hX);
  // layer 2: 256 -> 128
  k_fused<256, 128, true><<<dim3(625, 1, 2), 256, 0, stream>>>(
      ssrc, off, hX, bt2, b2, d_out);
}

// Round 12
// 418.617 us; speedup vs baseline: 1.7601x; 1.0040x over previous
//
#include <hip/hip_runtime.h>
#include <hip/hip_bf16.h>

#define NN 20000
#define EE 320000
#define RR 8
#define NR (NN * RR)
#define NB 40     // scan blocks per graph: ceil(160000/4096)
#define SCAP 640  // LDS edge-window capacity for 32 rows (mean 512, sd ~23)

typedef float f32x4 __attribute__((ext_vector_type(4)));
typedef short s16x8 __attribute__((ext_vector_type(8)));

__device__ __forceinline__ unsigned short f2bf(float f) {
  unsigned u = __builtin_bit_cast(unsigned, f);
  unsigned r = u + 0x7FFFu + ((u >> 16) & 1u);
  return (unsigned short)(r >> 16);
}
__device__ __forceinline__ float bf2f(unsigned short u) {
  return __builtin_bit_cast(float, (unsigned)u << 16);
}
__device__ __forceinline__ void gload_lds16(const void* g, void* l) {
  __builtin_amdgcn_global_load_lds(
      (const __attribute__((address_space(1))) unsigned*)g,
      (__attribute__((address_space(3))) unsigned*)l, 16, 0, 0);
}

// ---- per-(graph,dst,relation) segment count, both graphs ----
__global__ void k_count(const int* __restrict__ ei, const int* __restrict__ et,
                        int* __restrict__ cnt) {
  int e = blockIdx.x * blockDim.x + threadIdx.x;  // 0..2*EE
  int g = e >= EE;
  int el = e - g * EE;
  int d = ei[(size_t)g * 2 * EE + EE + el];
  int t = et[(size_t)g * EE + el];
  atomicAdd(&cnt[(size_t)g * NR + d * RR + t], 1);
}

// ---- hierarchical exclusive scan ----
__global__ __launch_bounds__(1024) void k_scan1(const int* __restrict__ cnt,
                                                int* __restrict__ off,
                                                int* __restrict__ btot) {
  int g = blockIdx.y, b = blockIdx.x;
  const int* c = cnt + (size_t)g * NR;
  int* o = off + (size_t)g * NR;
  __shared__ int wsum[16];
  int lane = threadIdx.x & 63, w = threadIdx.x >> 6;
  int i = b * 4096 + (int)threadIdx.x * 4;
  int4 v = {0, 0, 0, 0};
  if (i + 3 < NR) v = *(const int4*)&c[i];
  else {
    if (i < NR) v.x = c[i];
    if (i + 1 < NR) v.y = c[i + 1];
    if (i + 2 < NR) v.z = c[i + 2];
  }
  int s0 = v.x, s1 = s0 + v.y, s2 = s1 + v.z, s3 = s2 + v.w;
  int s = s3;
  for (int d = 1; d < 64; d <<= 1) {
    int t = __shfl_up(s, d);
    if (lane >= d) s += t;
  }
  if (lane == 63) wsum[w] = s;
  __syncthreads();
  if (threadIdx.x < 16) {
    int ws = wsum[threadIdx.x];
    for (int d = 1; d < 16; d <<= 1) {
      int t = __shfl_up(ws, d);
      if ((int)threadIdx.x >= d) ws += t;
    }
    wsum[threadIdx.x] = ws;
  }
  __syncthreads();
  int excl = (w > 0 ? wsum[w - 1] : 0) + (s - s3);
  if (i < NR) o[i] = excl;
  if (i + 1 < NR) o[i + 1] = excl + s0;
  if (i + 2 < NR) o[i + 2] = excl + s1;
  if (i + 3 < NR) o[i + 3] = excl + s2;
  if (threadIdx.x == 0) btot[g * NB + b] = wsum[15];
}

__global__ void k_scan2(const int* __restrict__ btot, int* __restrict__ bof) {
  int g = threadIdx.x >> 6, lane = threadIdx.x & 63;
  int v = (lane < NB) ? btot[g * NB + lane] : 0;
  int s = v;
  for (int d = 1; d < 64; d <<= 1) {
    int t = __shfl_up(s, d);
    if (lane >= d) s += t;
  }
  if (lane < NB) bof[g * NB + lane] = s - v;
}

__global__ __launch_bounds__(1024) void k_scan3(int* __restrict__ off,
                                                const int* __restrict__ bof) {
  int g = blockIdx.y;
  int add = bof[g * NB + blockIdx.x];
  int i = blockIdx.x * 4096 + (int)threadIdx.x * 4;
  int* o = off + (size_t)g * NR;
  if (i + 3 < NR) {
    int4 v = *(const int4*)&o[i];
    v.x += add; v.y += add; v.z += add; v.w += add;
    *(int4*)&o[i] = v;
  } else {
    for (int j = i; j < NR; ++j) o[j] += add;
  }
}

// ---- scatter src ids; DESTROYS off: post-scatter off[s] = end of segment s ----
__global__ void k_scatter(const int* __restrict__ ei, const int* __restrict__ et,
                          int* __restrict__ off, int* __restrict__ ssrc) {
  int e = blockIdx.x * blockDim.x + threadIdx.x;
  int g = e >= EE;
  int el = e - g * EE;
  int s = ei[(size_t)g * 2 * EE + el];
  int d = ei[(size_t)g * 2 * EE + EE + el];
  int t = et[(size_t)g * EE + el];
  int pos = atomicAdd(&off[(size_t)g * NR + d * RR + t], 1);
  ssrc[(size_t)g * EE + pos] = s;
}

// ---- fp32 x -> bf16, both graphs, into per-graph NN*256-strided slots ----
__global__ void k_cvt(const float* __restrict__ x, unsigned short* __restrict__ hX) {
  int i = (blockIdx.x * blockDim.x + threadIdx.x) * 4;
  if (i >= 2 * NN * 128) return;
  int g = i >= NN * 128;
  int il = i - g * NN * 128;
  float4 v = *(const float4*)&x[i];
  ushort4 o;
  o.x = f2bf(v.x); o.y = f2bf(v.y); o.z = f2bf(v.z); o.w = f2bf(v.w);
  *(ushort4*)&hX[(size_t)g * NN * 256 + il] = o;
}

// ---- fragment-ordered bf16 weight panel:
// btf[((s*(Cout/16)+fr)*2+kk)*512 + lane*8 + j] = BT[co][k]
//   co = fr*16 + (lane&15);  k = s*64 + kk*32 + (lane>>4)*8 + j  (r=8 -> root)
__global__ void k_btf(const float* __restrict__ W, const float* __restrict__ root,
                      unsigned short* __restrict__ btf, int Cin, int Cout,
                      int Ktot) {
  int idx = blockIdx.x * blockDim.x + threadIdx.x;
  if (idx >= Cout * Ktot) return;
  int j = idx & 7;
  int lane = (idx >> 3) & 63;
  int kk = (idx >> 9) & 1;
  int t = idx >> 10;  // s*(Cout/16) + fr
  int fr = t % (Cout / 16);
  int s = t / (Cout / 16);
  int co = fr * 16 + (lane & 15);
  int k = s * 64 + kk * 32 + (lane >> 4) * 8 + j;
  int r = k / Cin, ci = k - r * Cin;
  float v = (r < RR) ? W[((size_t)r * Cin + ci) * Cout + co]
                     : root[(size_t)ci * Cout + co];
  btf[idx] = f2bf(v);
}

// coalesced B-frag load for step s: per (kk,f) 64 lanes read contiguous 1KB
#define LOADB(bb, s)                                                           \
  _Pragma("unroll") for (int kk = 0; kk < 2; ++kk)                             \
      _Pragma("unroll") for (int f = 0; f < 4; ++f) bb[kk][f] =                \
          *(const s16x8*)(btl +                                                \
                          (size_t)(((s) * (COUT / 16) + wn16 + f) * 2 + kk) *  \
                              512);

#define COPYB()                                                                \
  _Pragma("unroll") for (int kk = 0; kk < 2; ++kk)                             \
      _Pragma("unroll") for (int f = 0; f < 4; ++f) bc[kk][f] = bn[kk][f];

// MFMA over As sub-tile c with B regs bb (As stride ASTR breaks bank alignment)
#define MFMA_STEP_C(c, bb)                                                     \
  do {                                                                         \
    _Pragma("unroll") for (int kk = 0; kk < 2; ++kk) {                         \
      s16x8 a[MF];                                                             \
      _Pragma("unroll") for (int f = 0; f < MF; ++f) {                         \
        int row = wm + f * 16 + (lane & 15);                                   \
        int colb = kk * 64 + (lane >> 4) * 16;                                 \
        a[f] = *(const s16x8*)(As + (c)*ASTR + row * 128 +                     \
                               (colb ^ ((row & 7) << 4)));                     \
      }                                                                        \
      _Pragma("unroll") for (int fm = 0; fm < MF; ++fm)                        \
          _Pragma("unroll") for (int fn = 0; fn < 4; ++fn)                     \
              acc[fm][fn] = __builtin_amdgcn_mfma_f32_16x16x32_bf16(           \
                  a[fm], bb[kk][fn], acc[fm][fn], 0, 0, 0);                    \
    }                                                                          \
  } while (0)

// pipelined walk: issue a pair of edges' h-loads into named register set S
#define WISSUE(S, ea, eb)                                                      \
  {                                                                            \
    int sa_ = inl ? sseg[(ea)-ebase] : ssrc[(ea)];                             \
    int sb_ = inl ? sseg[(eb)-ebase] : ssrc[(eb)];                             \
    const unsigned short* pa_ = hq + (size_t)sa_ * CIN;                        \
    const unsigned short* pb_ = hq + (size_t)sb_ * CIN;                        \
    _Pragma("unroll") for (int c = 0; c < NCH; ++c) {                          \
      va##S[c] = *(const s16x8*)(pa_ + c * 8);                                 \
      vb##S[c] = *(const s16x8*)(pb_ + c * 8);                                 \
    }                                                                          \
  }
#define WACC(S)                                                                \
  _Pragma("unroll") for (int c = 0; c < NCH; ++c)                              \
      _Pragma("unroll") for (int j = 0; j < 8; ++j)                            \
          fa[c][j] += bf2f((unsigned short)va##S[c][j]) +                      \
                      bf2f((unsigned short)vb##S[c][j]);

// ---- fused gather+GEMM, 32-row x COUT tile, relation-granular barriers,
//      B in registers (fragment-ordered), software-pipelined segment walk ----
template <int CIN, int COUT, bool OUTF32>
__global__ __launch_bounds__(256) void k_fused(
    const int* __restrict__ ssrc, const int* __restrict__ off,
    const unsigned short* __restrict__ h, const unsigned short* __restrict__ btf,
    const float* __restrict__ bias, void* __restrict__ outp) {
  constexpr int KTOT = (RR + 1) * CIN;
  constexpr int NS = KTOT / 64;    // flat K-steps (18 or 36)
  constexpr int CH = CIN / 64;     // sub-tiles per relation (2 or 4)
  constexpr int CPT = CIN / 8;     // cols per thread in walk (16 or 32)
  constexpr int NCH = CPT / 8;     // 16B chunks per thread (2 or 4)
  constexpr int NWN = COUT / 64;   // n-waves (4 or 2)
  constexpr int MW = 4 / NWN;      // m-waves (1 or 2)
  constexpr int WR = 32 / MW;      // rows per wave (32 or 16)
  constexpr int MF = WR / 16;      // m-frags per wave (2 or 1)
  constexpr int ASTR = 4112;       // padded sub-tile stride (4096+16, not %128)
  __shared__ char As[CH * ASTR];
  __shared__ int offs[32][9];      // per-row segment boundaries (start + 8 ends)
  __shared__ int sseg[SCAP];       // this block's sorted-edge window
  const int tid = threadIdx.x, lane = tid & 63, wave = tid >> 6;
  const int wn = (wave % NWN) * 64;
  const int wn16 = wn >> 4;
  const int wm = (wave / NWN) * WR;
  const int m0 = blockIdx.x * 32;  // NN == 625*32, no clamps needed
  const int g = blockIdx.z;
  ssrc += (size_t)g * EE;
  off += (size_t)g * NR;
  h += (size_t)g * NN * 256;

  for (int idx = tid; idx < 32 * 9; idx += 256) {
    int row = idx / 9, j = idx - row * 9;
    int seg0 = (m0 + row) * RR;
    offs[row][j] = (j == 0) ? (seg0 == 0 ? 0 : off[seg0 - 1]) : off[seg0 + j - 1];
  }
  const int segA = m0 * RR;
  const int ebase = (segA == 0) ? 0 : off[segA - 1];
  const int eend = off[(m0 + 32) * RR - 1];
  const int cntE = eend - ebase;
  const bool inl = cntE <= SCAP;
  if (inl)
    for (int i = tid; i < cntE; i += 256) sseg[i] = ssrc[ebase + i];
  __syncthreads();

  f32x4 acc[MF][4] = {};
  const int arow = tid >> 3;              // this thread's A row (0..31)
  const int q = tid & 7;                  // 8 threads/row, CPT cols each
  const int swzA = (arow & 7) << 4;
  const unsigned short* hq = h + q * CPT;
  const unsigned short* btl = btf + lane * 8;

  s16x8 bc[2][4], bn[2][4];
  LOADB(bc, 0);

  // walk pipeline register sets (persist across phases for cross-phase prefetch)
  s16x8 vaA[NCH], vbA[NCH], vaB[NCH], vbB[NCH];
  bool pfv = false;  // set A holds a prefetched pair for the upcoming relation

  for (int r = 0; r <= RR; ++r) {
    s16x8 mb[NCH];
    if (r < RR) {
      // ---- software-pipelined segment walk (pairs ping-pong A/B) ----
      float fa[NCH][8];
#pragma unroll
      for (int c = 0; c < NCH; ++c)
#pragma unroll
        for (int j = 0; j < 8; ++j) fa[c][j] = 0.f;
      const int o0v = offs[arow][r];
      const int o1 = offs[arow][r + 1];
      int e = pfv ? o0v + 2 : o0v;
      bool pA = pfv, pB = false;
      if (!pA && e + 1 < o1) { WISSUE(A, e, e + 1); e += 2; pA = true; }
      while (pA) {
        if (e + 1 < o1) { WISSUE(B, e, e + 1); e += 2; pB = true; }
        WACC(A);
        pA = false;
        if (pB) {
          if (e + 1 < o1) { WISSUE(A, e, e + 1); e += 2; pA = true; }
          WACC(B);
          pB = false;
        }
      }
      if (e < o1) {  // odd tail edge
        int sa_ = inl ? sseg[e - ebase] : ssrc[e];
        const unsigned short* pa_ = hq + (size_t)sa_ * CIN;
#pragma unroll
        for (int c = 0; c < NCH; ++c) {
          s16x8 va_ = *(const s16x8*)(pa_ + c * 8);
#pragma unroll
          for (int j = 0; j < 8; ++j) fa[c][j] += bf2f((unsigned short)va_[j]);
        }
      }
      float inv = 1.0f / fmaxf((float)(o1 - o0v), 1.0f);
#pragma unroll
      for (int c = 0; c < NCH; ++c)
#pragma unroll
        for (int j = 0; j < 8; ++j) mb[c][j] = (short)f2bf(fa[c][j] * inv);
      // ---- cross-phase prefetch: first pair of NEXT relation's segment ----
      pfv = false;
      if (r + 1 < RR) {
        int no1 = offs[arow][r + 2];
        if (o1 + 1 < no1) { WISSUE(A, o1, o1 + 1); pfv = true; }
      }
    }
    __syncthreads();  // prior relation's MFMA done reading As
    if (r < RR) {
      // write this thread's CPT cols into padded sub-tile-major swizzled As
#pragma unroll
      for (int ch = 0; ch < NCH; ++ch) {
        int colb = (q * CPT + ch * 8) * 2;  // byte col in full CIN row
        int ct = colb >> 7;                 // sub-tile index
        int wb = colb & 127;                // byte within 128-B window
        *(s16x8*)(As + ct * ASTR + arow * 128 + (wb ^ swzA)) = mb[ch];
      }
    } else {
      // root term: stage h rows via global_load_lds (pre-swizzled source)
#pragma unroll
      for (int i = 0; i < CH; ++i) {
        int o = i * ASTR + wave * 1024;  // wave-uniform LDS base
        int ob = wave * 1024 + lane * 16;
        int row = (ob >> 7) & 31;
        int wb = ob & 127;
        gload_lds16((const char*)h + ((size_t)(m0 + row) * CIN + i * 64) * 2 +
                        (wb ^ ((row & 7) << 4)),
                    As + o);
      }
    }
    __syncthreads();  // As visible (drains gload_lds / ds_writes)
#pragma unroll
    for (int c = 0; c < CH; ++c) {
      int s = r * CH + c;
      if (s + 1 < NS) { LOADB(bn, s + 1); }
      MFMA_STEP_C(c, bc);
      if (s + 1 < NS) { COPYB(); }
    }
  }
  // ---- epilogue: bias + LeakyReLU ----
#pragma unroll
  for (int fm = 0; fm < MF; ++fm) {
    int rbase = m0 + wm + fm * 16 + (lane >> 4) * 4;
#pragma unroll
    for (int fn = 0; fn < 4; ++fn) {
      int col = wn + fn * 16 + (lane & 15);
      float bv = bias[col];
#pragma unroll
      for (int v = 0; v < 4; ++v) {
        int row = rbase + v;
        float xv = acc[fm][fn][v] + bv;
        xv = xv > 0.f ? xv : 0.2f * xv;
        if constexpr (OUTF32)
          ((float*)outp)[(size_t)g * NN * COUT + (size_t)row * COUT + col] = xv;
        else
          ((unsigned short*)outp)[(size_t)g * NN * 256 + (size_t)row * COUT +
                                  col] = f2bf(xv);
      }
    }
  }
}

extern "C" void kernel_launch(void* const* d_in, const int* in_sizes, int n_in,
                              void* d_out, int out_size, void* d_ws, size_t ws_size,
                              hipStream_t stream) {
  const float* x  = (const float*)d_in[0];
  const int* ei   = (const int*)d_in[1];
  const int* etp  = (const int*)d_in[2];
  const float* W0 = (const float*)d_in[3];
  const float* r0 = (const float*)d_in[4];
  const float* b0 = (const float*)d_in[5];
  const float* W1 = (const float*)d_in[6];
  const float* r1 = (const float*)d_in[7];
  const float* b1 = (const float*)d_in[8];
  const float* W2 = (const float*)d_in[9];
  const float* r2 = (const float*)d_in[10];
  const float* b2 = (const float*)d_in[11];

  char* p = (char*)d_ws;
  unsigned short* hX  = (unsigned short*)p; p += (size_t)2 * NN * 256 * 2;
  unsigned short* h_a = (unsigned short*)p; p += (size_t)2 * NN * 256 * 2;
  int* cnt  = (int*)p; p += (size_t)2 * NR * 4;
  int* off  = (int*)p; p += (size_t)2 * NR * 4;
  int* btot = (int*)p; p += (size_t)2 * NB * 4;
  int* bof  = (int*)p; p += (size_t)2 * NB * 4;
  int* ssrc = (int*)p; p += (size_t)2 * EE * 4;
  unsigned short* bt0 = (unsigned short*)p; p += (size_t)256 * 1152 * 2;
  unsigned short* bt1 = (unsigned short*)p; p += (size_t)256 * 2304 * 2;
  unsigned short* bt2 = (unsigned short*)p; p += (size_t)128 * 2304 * 2;

  // fragment-ordered weight panels (graph-independent)
  k_btf<<<(256 * 1152 + 255) / 256, 256, 0, stream>>>(W0, r0, bt0, 128, 256, 1152);
  k_btf<<<(256 * 2304 + 255) / 256, 256, 0, stream>>>(W1, r1, bt1, 256, 256, 2304);
  k_btf<<<(128 * 2304 + 255) / 256, 256, 0, stream>>>(W2, r2, bt2, 256, 128, 2304);

  // edge sort (both graphs batched)
  (void)hipMemsetAsync(cnt, 0, (size_t)2 * NR * 4, stream);
  k_count<<<2 * EE / 256, 256, 0, stream>>>(ei, etp, cnt);
  k_scan1<<<dim3(NB, 2), 1024, 0, stream>>>(cnt, off, btot);
  k_scan2<<<1, 128, 0, stream>>>(btot, bof);
  k_scan3<<<dim3(NB, 2), 1024, 0, stream>>>(off, bof);
  k_cvt<<<2 * NN * 128 / 4 / 256, 256, 0, stream>>>(x, hX);
  k_scatter<<<2 * EE / 256, 256, 0, stream>>>(ei, etp, off, ssrc);

  // layer 0: 128 -> 256 (fused gather+GEMM)
  k_fused<128, 256, false><<<dim3(625, 1, 2), 256, 0, stream>>>(
      ssrc, off, hX, bt0, b0, h_a);
  // layer 1: 256 -> 256
  k_fused<256, 256, false><<<dim3(625, 1, 2), 256, 0, stream>>>(
      ssrc, off, h_a, bt1, b1, hX);
  // layer 2: 256 -> 128
  k_fused<256, 128, true><<<dim3(625, 1, 2), 256, 0, stream>>>(
      ssrc, off, hX, bt2, b2, d_out);
}

// Round 13
// 387.352 us; speedup vs baseline: 1.9022x; 1.0807x over previous
//
#include <hip/hip_runtime.h>
#include <hip/hip_bf16.h>

#define NN 20000
#define EE 320000
#define RR 8
#define NR (NN * RR)
#define NB 40     // scan blocks per graph: ceil(160000/4096)
#define SCAP 640  // LDS edge-window capacity for 32 rows (mean 512, sd ~23)

typedef float f32x4 __attribute__((ext_vector_type(4)));
typedef short s16x8 __attribute__((ext_vector_type(8)));

__device__ __forceinline__ unsigned short f2bf(float f) {
  unsigned u = __builtin_bit_cast(unsigned, f);
  unsigned r = u + 0x7FFFu + ((u >> 16) & 1u);
  return (unsigned short)(r >> 16);
}
__device__ __forceinline__ float bf2f(unsigned short u) {
  return __builtin_bit_cast(float, (unsigned)u << 16);
}
__device__ __forceinline__ void gload_lds16(const void* g, void* l) {
  __builtin_amdgcn_global_load_lds(
      (const __attribute__((address_space(1))) unsigned*)g,
      (__attribute__((address_space(3))) unsigned*)l, 16, 0, 0);
}

// ---- per-(graph,dst,relation) segment count, both graphs ----
__global__ void k_count(const int* __restrict__ ei, const int* __restrict__ et,
                        int* __restrict__ cnt) {
  int e = blockIdx.x * blockDim.x + threadIdx.x;  // 0..2*EE
  int g = e >= EE;
  int el = e - g * EE;
  int d = ei[(size_t)g * 2 * EE + EE + el];
  int t = et[(size_t)g * EE + el];
  atomicAdd(&cnt[(size_t)g * NR + d * RR + t], 1);
}

// ---- hierarchical exclusive scan ----
__global__ __launch_bounds__(1024) void k_scan1(const int* __restrict__ cnt,
                                                int* __restrict__ off,
                                                int* __restrict__ btot) {
  int g = blockIdx.y, b = blockIdx.x;
  const int* c = cnt + (size_t)g * NR;
  int* o = off + (size_t)g * NR;
  __shared__ int wsum[16];
  int lane = threadIdx.x & 63, w = threadIdx.x >> 6;
  int i = b * 4096 + (int)threadIdx.x * 4;
  int4 v = {0, 0, 0, 0};
  if (i + 3 < NR) v = *(const int4*)&c[i];
  else {
    if (i < NR) v.x = c[i];
    if (i + 1 < NR) v.y = c[i + 1];
    if (i + 2 < NR) v.z = c[i + 2];
  }
  int s0 = v.x, s1 = s0 + v.y, s2 = s1 + v.z, s3 = s2 + v.w;
  int s = s3;
  for (int d = 1; d < 64; d <<= 1) {
    int t = __shfl_up(s, d);
    if (lane >= d) s += t;
  }
  if (lane == 63) wsum[w] = s;
  __syncthreads();
  if (threadIdx.x < 16) {
    int ws = wsum[threadIdx.x];
    for (int d = 1; d < 16; d <<= 1) {
      int t = __shfl_up(ws, d);
      if ((int)threadIdx.x >= d) ws += t;
    }
    wsum[threadIdx.x] = ws;
  }
  __syncthreads();
  int excl = (w > 0 ? wsum[w - 1] : 0) + (s - s3);
  if (i < NR) o[i] = excl;
  if (i + 1 < NR) o[i + 1] = excl + s0;
  if (i + 2 < NR) o[i + 2] = excl + s1;
  if (i + 3 < NR) o[i + 3] = excl + s2;
  if (threadIdx.x == 0) btot[g * NB + b] = wsum[15];
}

__global__ void k_scan2(const int* __restrict__ btot, int* __restrict__ bof) {
  int g = threadIdx.x >> 6, lane = threadIdx.x & 63;
  int v = (lane < NB) ? btot[g * NB + lane] : 0;
  int s = v;
  for (int d = 1; d < 64; d <<= 1) {
    int t = __shfl_up(s, d);
    if (lane >= d) s += t;
  }
  if (lane < NB) bof[g * NB + lane] = s - v;
}

__global__ __launch_bounds__(1024) void k_scan3(int* __restrict__ off,
                                                const int* __restrict__ bof) {
  int g = blockIdx.y;
  int add = bof[g * NB + blockIdx.x];
  int i = blockIdx.x * 4096 + (int)threadIdx.x * 4;
  int* o = off + (size_t)g * NR;
  if (i + 3 < NR) {
    int4 v = *(const int4*)&o[i];
    v.x += add; v.y += add; v.z += add; v.w += add;
    *(int4*)&o[i] = v;
  } else {
    for (int j = i; j < NR; ++j) o[j] += add;
  }
}

// ---- scatter src ids; DESTROYS off: post-scatter off[s] = end of segment s ----
__global__ void k_scatter(const int* __restrict__ ei, const int* __restrict__ et,
                          int* __restrict__ off, int* __restrict__ ssrc) {
  int e = blockIdx.x * blockDim.x + threadIdx.x;
  int g = e >= EE;
  int el = e - g * EE;
  int s = ei[(size_t)g * 2 * EE + el];
  int d = ei[(size_t)g * 2 * EE + EE + el];
  int t = et[(size_t)g * EE + el];
  int pos = atomicAdd(&off[(size_t)g * NR + d * RR + t], 1);
  ssrc[(size_t)g * EE + pos] = s;
}

// ---- fp32 x -> bf16, both graphs, into per-graph NN*256-strided slots ----
__global__ void k_cvt(const float* __restrict__ x, unsigned short* __restrict__ hX) {
  int i = (blockIdx.x * blockDim.x + threadIdx.x) * 4;
  if (i >= 2 * NN * 128) return;
  int g = i >= NN * 128;
  int il = i - g * NN * 128;
  float4 v = *(const float4*)&x[i];
  ushort4 o;
  o.x = f2bf(v.x); o.y = f2bf(v.y); o.z = f2bf(v.z); o.w = f2bf(v.w);
  *(ushort4*)&hX[(size_t)g * NN * 256 + il] = o;
}

// ---- fragment-ordered bf16 weight panel:
// btf[((s*(Cout/16)+fr)*2+kk)*512 + lane*8 + j] = BT[co][k]
//   co = fr*16 + (lane&15);  k = s*64 + kk*32 + (lane>>4)*8 + j  (r=8 -> root)
__global__ void k_btf(const float* __restrict__ W, const float* __restrict__ root,
                      unsigned short* __restrict__ btf, int Cin, int Cout,
                      int Ktot) {
  int idx = blockIdx.x * blockDim.x + threadIdx.x;
  if (idx >= Cout * Ktot) return;
  int j = idx & 7;
  int lane = (idx >> 3) & 63;
  int kk = (idx >> 9) & 1;
  int t = idx >> 10;  // s*(Cout/16) + fr
  int fr = t % (Cout / 16);
  int s = t / (Cout / 16);
  int co = fr * 16 + (lane & 15);
  int k = s * 64 + kk * 32 + (lane >> 4) * 8 + j;
  int r = k / Cin, ci = k - r * Cin;
  float v = (r < RR) ? W[((size_t)r * Cin + ci) * Cout + co]
                     : root[(size_t)ci * Cout + co];
  btf[idx] = f2bf(v);
}

// coalesced B-frag load for step s: per (kk,f) 64 lanes read contiguous 1KB
#define LOADB(bb, s)                                                           \
  _Pragma("unroll") for (int kk = 0; kk < 2; ++kk)                             \
      _Pragma("unroll") for (int f = 0; f < 4; ++f) bb[kk][f] =                \
          *(const s16x8*)(btl +                                                \
                          (size_t)(((s) * (COUT / 16) + wn16 + f) * 2 + kk) *  \
                              512);

#define COPYB()                                                                \
  _Pragma("unroll") for (int kk = 0; kk < 2; ++kk)                             \
      _Pragma("unroll") for (int f = 0; f < 4; ++f) bc[kk][f] = bn[kk][f];

// MFMA over sub-tile c of buffer Ab with B regs bb
#define MFMA_STEP_C(Ab, c, bb)                                                 \
  do {                                                                         \
    _Pragma("unroll") for (int kk = 0; kk < 2; ++kk) {                         \
      s16x8 a[MF];                                                             \
      _Pragma("unroll") for (int f = 0; f < MF; ++f) {                         \
        int row = wm + f * 16 + (lane & 15);                                   \
        int colb = kk * 64 + (lane >> 4) * 16;                                 \
        a[f] = *(const s16x8*)((Ab) + (c)*ASTR + row * 128 +                   \
                               (colb ^ ((row & 7) << 4)));                     \
      }                                                                        \
      _Pragma("unroll") for (int fm = 0; fm < MF; ++fm)                        \
          _Pragma("unroll") for (int fn = 0; fn < 4; ++fn)                     \
              acc[fm][fn] = __builtin_amdgcn_mfma_f32_16x16x32_bf16(           \
                  a[fm], bb[kk][fn], acc[fm][fn], 0, 0, 0);                    \
    }                                                                          \
  } while (0)

// accumulate one uint4 (8 bf16) into split hi/lo f32 banks: 2 VALU/element
#define ACC4(u)                                                                \
  {                                                                            \
    faH[c][0] += __builtin_bit_cast(float, (u).x & 0xFFFF0000u);               \
    faL[c][0] += __builtin_bit_cast(float, (u).x << 16);                       \
    faH[c][1] += __builtin_bit_cast(float, (u).y & 0xFFFF0000u);               \
    faL[c][1] += __builtin_bit_cast(float, (u).y << 16);                       \
    faH[c][2] += __builtin_bit_cast(float, (u).z & 0xFFFF0000u);               \
    faL[c][2] += __builtin_bit_cast(float, (u).z << 16);                       \
    faH[c][3] += __builtin_bit_cast(float, (u).w & 0xFFFF0000u);               \
    faL[c][3] += __builtin_bit_cast(float, (u).w << 16);                       \
  }

// ---- fused gather+GEMM, 32-row x COUT tile, double-buffered As,
//      ONE barrier per relation, B in registers (fragment-ordered) ----
template <int CIN, int COUT, bool OUTF32>
__global__ __launch_bounds__(256) void k_fused(
    const int* __restrict__ ssrc, const int* __restrict__ off,
    const unsigned short* __restrict__ h, const unsigned short* __restrict__ btf,
    const float* __restrict__ bias, void* __restrict__ outp) {
  constexpr int KTOT = (RR + 1) * CIN;
  constexpr int NS = KTOT / 64;    // flat K-steps (18 or 36)
  constexpr int CH = CIN / 64;     // sub-tiles per relation (2 or 4)
  constexpr int CPT = CIN / 8;     // cols per thread in walk (16 or 32)
  constexpr int NCH = CPT / 8;     // 16B chunks per thread (2 or 4)
  constexpr int NWN = COUT / 64;   // n-waves (4 or 2)
  constexpr int MW = 4 / NWN;      // m-waves (1 or 2)
  constexpr int WR = 32 / MW;      // rows per wave (32 or 16)
  constexpr int MF = WR / 16;      // m-frags per wave (2 or 1)
  constexpr int ASTR = 4112;       // padded sub-tile stride (4096+16, not %128)
  __shared__ char As[2][CH * ASTR];  // double-buffered at relation granularity
  __shared__ int offs[32][9];      // per-row segment boundaries (start + 8 ends)
  __shared__ int sseg[SCAP];       // this block's sorted-edge window
  const int tid = threadIdx.x, lane = tid & 63, wave = tid >> 6;
  const int wn = (wave % NWN) * 64;
  const int wn16 = wn >> 4;
  const int wm = (wave / NWN) * WR;
  const int m0 = blockIdx.x * 32;  // NN == 625*32, no clamps needed
  const int g = blockIdx.z;
  ssrc += (size_t)g * EE;
  off += (size_t)g * NR;
  h += (size_t)g * NN * 256;

  for (int idx = tid; idx < 32 * 9; idx += 256) {
    int row = idx / 9, j = idx - row * 9;
    int seg0 = (m0 + row) * RR;
    offs[row][j] = (j == 0) ? (seg0 == 0 ? 0 : off[seg0 - 1]) : off[seg0 + j - 1];
  }
  const int segA = m0 * RR;
  const int ebase = (segA == 0) ? 0 : off[segA - 1];
  const int eend = off[(m0 + 32) * RR - 1];
  const int cntE = eend - ebase;
  const bool inl = cntE <= SCAP;
  if (inl)
    for (int i = tid; i < cntE; i += 256) sseg[i] = ssrc[ebase + i];
  __syncthreads();

  f32x4 acc[MF][4] = {};
  const int arow = tid >> 3;              // this thread's A row (0..31)
  const int q = tid & 7;                  // 8 threads/row, CPT cols each
  const int swzA = (arow & 7) << 4;
  const unsigned short* hq = h + q * CPT;
  const unsigned short* btl = btf + lane * 8;

  // walk relation r's segment, write per-relation means into As[buf]
  auto produce = [&](int r, int buf) {
    float faL[NCH][4], faH[NCH][4];
#pragma unroll
    for (int c = 0; c < NCH; ++c)
#pragma unroll
      for (int w = 0; w < 4; ++w) { faL[c][w] = 0.f; faH[c][w] = 0.f; }
    int o0 = offs[arow][r], o1 = offs[arow][r + 1];
    int e = o0;
    for (; e + 1 < o1; e += 2) {
      int sa = inl ? sseg[e - ebase] : ssrc[e];
      int sb = inl ? sseg[e + 1 - ebase] : ssrc[e + 1];
      const unsigned short* pa = hq + (size_t)sa * CIN;
      const unsigned short* pb = hq + (size_t)sb * CIN;
#pragma unroll
      for (int c = 0; c < NCH; ++c) {
        uint4 ua = *(const uint4*)(pa + c * 8);
        uint4 ub = *(const uint4*)(pb + c * 8);
        ACC4(ua);
        ACC4(ub);
      }
    }
    if (e < o1) {
      int sa = inl ? sseg[e - ebase] : ssrc[e];
      const unsigned short* pa = hq + (size_t)sa * CIN;
#pragma unroll
      for (int c = 0; c < NCH; ++c) {
        uint4 ua = *(const uint4*)(pa + c * 8);
        ACC4(ua);
      }
    }
    float inv = 1.0f / fmaxf((float)(o1 - o0), 1.0f);
#pragma unroll
    for (int c = 0; c < NCH; ++c) {
      s16x8 mbv;
#pragma unroll
      for (int w = 0; w < 4; ++w) {
        mbv[2 * w] = (short)f2bf(faL[c][w] * inv);
        mbv[2 * w + 1] = (short)f2bf(faH[c][w] * inv);
      }
      int colb = (q * CPT + c * 8) * 2;  // byte col in full CIN row
      int ct = colb >> 7;                // sub-tile index
      int wb = colb & 127;               // byte within 128-B window
      *(s16x8*)(As[buf] + ct * ASTR + arow * 128 + (wb ^ swzA)) = mbv;
    }
  };

  // root term: stage h rows directly via global_load_lds (pre-swizzled source)
  auto root_stage = [&]() {
#pragma unroll
    for (int i = 0; i < CH; ++i) {
      int o = i * ASTR + wave * 1024;  // wave-uniform LDS base
      int ob = wave * 1024 + lane * 16;
      int row = (ob >> 7) & 31;
      int wb = ob & 127;
      gload_lds16((const char*)h + ((size_t)(m0 + row) * CIN + i * 64) * 2 +
                      (wb ^ ((row & 7) << 4)),
                  As[RR & 1] + o);
    }
  };

  s16x8 bc[2][4], bn[2][4];
  LOADB(bc, 0);
  produce(0, 0);
  __syncthreads();

  for (int r = 0; r <= RR; ++r) {
    const char* Ab = As[r & 1];
#pragma unroll
    for (int c = 0; c < CH; ++c) {
      int s = r * CH + c;
      if (s + 1 < NS) { LOADB(bn, s + 1); }
      MFMA_STEP_C(Ab, c, bc);
      if (s + 1 < NS) { COPYB(); }
    }
    // produce next buffer while the matrix pipe drains
    if (r + 1 < RR) produce(r + 1, (r + 1) & 1);
    else if (r + 1 == RR) root_stage();
    __syncthreads();
  }

  // ---- epilogue: bias + LeakyReLU ----
#pragma unroll
  for (int fm = 0; fm < MF; ++fm) {
    int rbase = m0 + wm + fm * 16 + (lane >> 4) * 4;
#pragma unroll
    for (int fn = 0; fn < 4; ++fn) {
      int col = wn + fn * 16 + (lane & 15);
      float bv = bias[col];
#pragma unroll
      for (int v = 0; v < 4; ++v) {
        int row = rbase + v;
        float xv = acc[fm][fn][v] + bv;
        xv = xv > 0.f ? xv : 0.2f * xv;
        if constexpr (OUTF32)
          ((float*)outp)[(size_t)g * NN * COUT + (size_t)row * COUT + col] = xv;
        else
          ((unsigned short*)outp)[(size_t)g * NN * 256 + (size_t)row * COUT +
                                  col] = f2bf(xv);
      }
    }
  }
}

extern "C" void kernel_launch(void* const* d_in, const int* in_sizes, int n_in,
                              void* d_out, int out_size, void* d_ws, size_t ws_size,
                              hipStream_t stream) {
  const float* x  = (const float*)d_in[0];
  const int* ei   = (const int*)d_in[1];
  const int* etp  = (const int*)d_in[2];
  const float* W0 = (const float*)d_in[3];
  const float* r0 = (const float*)d_in[4];
  const float* b0 = (const float*)d_in[5];
  const float* W1 = (const float*)d_in[6];
  const float* r1 = (const float*)d_in[7];
  const float* b1 = (const float*)d_in[8];
  const float* W2 = (const float*)d_in[9];
  const float* r2 = (const float*)d_in[10];
  const float* b2 = (const float*)d_in[11];

  char* p = (char*)d_ws;
  unsigned short* hX  = (unsigned short*)p; p += (size_t)2 * NN * 256 * 2;
  unsigned short* h_a = (unsigned short*)p; p += (size_t)2 * NN * 256 * 2;
  int* cnt  = (int*)p; p += (size_t)2 * NR * 4;
  int* off  = (int*)p; p += (size_t)2 * NR * 4;
  int* btot = (int*)p; p += (size_t)2 * NB * 4;
  int* bof  = (int*)p; p += (size_t)2 * NB * 4;
  int* ssrc = (int*)p; p += (size_t)2 * EE * 4;
  unsigned short* bt0 = (unsigned short*)p; p += (size_t)256 * 1152 * 2;
  unsigned short* bt1 = (unsigned short*)p; p += (size_t)256 * 2304 * 2;
  unsigned short* bt2 = (unsigned short*)p; p += (size_t)128 * 2304 * 2;

  // fragment-ordered weight panels (graph-independent)
  k_btf<<<(256 * 1152 + 255) / 256, 256, 0, stream>>>(W0, r0, bt0, 128, 256, 1152);
  k_btf<<<(256 * 2304 + 255) / 256, 256, 0, stream>>>(W1, r1, bt1, 256, 256, 2304);
  k_btf<<<(128 * 2304 + 255) / 256, 256, 0, stream>>>(W2, r2, bt2, 256, 128, 2304);

  // edge sort (both graphs batched)
  (void)hipMemsetAsync(cnt, 0, (size_t)2 * NR * 4, stream);
  k_count<<<2 * EE / 256, 256, 0, stream>>>(ei, etp, cnt);
  k_scan1<<<dim3(NB, 2), 1024, 0, stream>>>(cnt, off, btot);
  k_scan2<<<1, 128, 0, stream>>>(btot, bof);
  k_scan3<<<dim3(NB, 2), 1024, 0, stream>>>(off, bof);
  k_cvt<<<2 * NN * 128 / 4 / 256, 256, 0, stream>>>(x, hX);
  k_scatter<<<2 * EE / 256, 256, 0, stream>>>(ei, etp, off, ssrc);

  // layer 0: 128 -> 256 (fused gather+GEMM)
  k_fused<128, 256, false><<<dim3(625, 1, 2), 256, 0, stream>>>(
      ssrc, off, hX, bt0, b0, h_a);
  // layer 1: 256 -> 256
  k_fused<256, 256, false><<<dim3(625, 1, 2), 256, 0, stream>>>(
      ssrc, off, h_a, bt1, b1, hX);
  // layer 2: 256 -> 128
  k_fused<256, 128, true><<<dim3(625, 1, 2), 256, 0, stream>>>(
      ssrc, off, hX, bt2, b2, d_out);
}